// Round 1
// baseline (476.725 us; speedup 1.0000x reference)
//
#include <hip/hip_runtime.h>
#include <math.h>

// ws layout (floats)
#define WK1F 0
#define WV1F 2048
#define WK2F 4096
#define WV2F 6144
#define BK1F 8192
#define BV1F 8256
#define BK2F 8320
#define BV2F 8384
#define Q1OF 8448
// total 8640 floats

struct Params {
  const float* tl; const float* tr;
  const float* qemb;
  const float* ip_w1; const float* ip_b1;
  const float* wq2; const float* bq2;
  const float* wo1; const float* bo1;
  const float* wo2; const float* bo2;
  const float* ffn_w1; const float* ffn_b1;
  const float* ffn_w2; const float* ffn_b2;
  const float* n1_g; const float* n1_b;
  const float* n2_g; const float* n2_b;
  const float* n3_g; const float* n3_b;
  const float* op_w1; const float* op_b1;
  const float* op_w2; const float* op_b2;
  const float* ws;
  float* out;
};

// Fold ip_w2@w and ip_b2@w + b for k/v of both layers; precompute q1 = qemb@wq1+bq1.
__global__ void prep_kernel(const float* ip_w2, const float* ip_b2,
                            const float* wk1, const float* bk1,
                            const float* wv1, const float* bv1,
                            const float* wk2, const float* bk2,
                            const float* wv2, const float* bv2,
                            const float* qemb, const float* wq1, const float* bq1,
                            float* ws) {
  const int bid = blockIdx.x, tid = threadIdx.x;
  if (bid < 32) {
    const int idx = bid * 256 + tid;   // 0..8191
    const int mat = idx >> 11;
    const int rem = idx & 2047;
    const int j = rem >> 6, c = rem & 63;
    const float* W = (mat == 0) ? wk1 : (mat == 1) ? wv1 : (mat == 2) ? wk2 : wv2;
    float acc = 0.f;
    for (int m = 0; m < 64; ++m) acc = fmaf(ip_w2[j * 64 + m], W[m * 64 + c], acc);
    ws[mat * 2048 + j * 64 + c] = acc;
  } else if (tid < 64) {
    const int c = tid;
    float a0 = bk1[c], a1 = bv1[c], a2 = bk2[c], a3 = bv2[c];
    for (int m = 0; m < 64; ++m) {
      const float bm = ip_b2[m];
      a0 = fmaf(bm, wk1[m * 64 + c], a0);
      a1 = fmaf(bm, wv1[m * 64 + c], a1);
      a2 = fmaf(bm, wk2[m * 64 + c], a2);
      a3 = fmaf(bm, wv2[m * 64 + c], a3);
    }
    ws[BK1F + c] = a0; ws[BV1F + c] = a1; ws[BK2F + c] = a2; ws[BV2F + c] = a3;
    for (int q = 0; q < 3; ++q) {
      float acc = bq1[c];
      for (int j = 0; j < 64; ++j) acc = fmaf(qemb[q * 64 + j], wq1[j * 64 + c], acc);
      ws[Q1OF + q * 64 + c] = acc;
    }
  }
}

__global__ __launch_bounds__(64) void planner_kernel(Params p) {
  const int item = blockIdx.x;
  const int lane = threadIdx.x;

  __shared__ __align__(16) float pts_s[40];
  __shared__ __align__(16) float a_s[20][32];   // relu activations
  __shared__ __align__(16) float k_s[20][66];   // stride 66: float2 reads conflict-free
  __shared__ __align__(16) float q_s[3][66];
  __shared__ __align__(16) float x_s[3][68];    // stride 68: float4-aligned rows
  __shared__ __align__(16) float o_s[3][68];
  __shared__ __align__(16) float w_att[12][21];
  __shared__ __align__(16) float f1_s[3][132];

  // P0: stage the 20 points (concat(left,right) flattened matches input layout)
  if (lane < 40)
    pts_s[lane] = (lane < 20) ? p.tl[item * 20 + lane] : p.tr[item * 20 + lane - 20];
  __syncthreads();

  // P1: a = relu(pts @ ip_w1 + ip_b1)   [20][32]
  {
    const int j = lane & 31, th = lane >> 5;
    const float w0 = p.ip_w1[j];
    const float w1 = p.ip_w1[32 + j];
    const float b = p.ip_b1[j];
#pragma unroll
    for (int i = 0; i < 10; ++i) {
      const int t = th * 10 + i;
      const float h = fmaf(pts_s[2 * t], w0, fmaf(pts_s[2 * t + 1], w1, b));
      a_s[t][j] = fmaxf(h, 0.f);
    }
  }
  __syncthreads();

  float xq[3];  // current x (post-LN), lane=channel
  const float* ws = p.ws;

#pragma unroll
  for (int l = 0; l < 2; ++l) {
    const float* Wkf = ws + (l ? WK2F : WK1F);
    const float* Wvf = ws + (l ? WV2F : WV1F);
    const float* bkf = ws + (l ? BK2F : BK1F);
    const float* bvf = ws + (l ? BV2F : BV1F);

    // Q for this layer
    if (l == 0) {
#pragma unroll
      for (int q = 0; q < 3; ++q) q_s[q][lane] = ws[Q1OF + q * 64 + lane];
    } else {
      float acc[3];
#pragma unroll
      for (int q = 0; q < 3; ++q) acc[q] = p.bq2[lane];
#pragma unroll
      for (int jc = 0; jc < 16; ++jc) {
        float w[4];
#pragma unroll
        for (int r = 0; r < 4; ++r) w[r] = p.wq2[(jc * 4 + r) * 64 + lane];
#pragma unroll
        for (int q = 0; q < 3; ++q) {
          const float4 xv = *reinterpret_cast<const float4*>(&x_s[q][jc * 4]);
          acc[q] = fmaf(xv.x, w[0], fmaf(xv.y, w[1], fmaf(xv.z, w[2], fmaf(xv.w, w[3], acc[q]))));
        }
      }
#pragma unroll
      for (int q = 0; q < 3; ++q) q_s[q][lane] = acc[q];
    }

    // KV projection from folded weights; k -> LDS, v stays in registers (lane=channel)
    float vacc[20];
    {
      float kacc[20];
      const float bk = bkf[lane], bv = bvf[lane];
#pragma unroll
      for (int t = 0; t < 20; ++t) { kacc[t] = bk; vacc[t] = bv; }
#pragma unroll
      for (int jc = 0; jc < 8; ++jc) {
        float wk[4], wv[4];
#pragma unroll
        for (int r = 0; r < 4; ++r) {
          wk[r] = Wkf[(jc * 4 + r) * 64 + lane];
          wv[r] = Wvf[(jc * 4 + r) * 64 + lane];
        }
#pragma unroll
        for (int t = 0; t < 20; ++t) {
          const float4 av = *reinterpret_cast<const float4*>(&a_s[t][jc * 4]);
          kacc[t] = fmaf(av.x, wk[0], fmaf(av.y, wk[1], fmaf(av.z, wk[2], fmaf(av.w, wk[3], kacc[t]))));
          vacc[t] = fmaf(av.x, wv[0], fmaf(av.y, wv[1], fmaf(av.z, wv[2], fmaf(av.w, wv[3], vacc[t]))));
        }
      }
#pragma unroll
      for (int t = 0; t < 20; ++t) k_s[t][lane] = kacc[t];
    }
    __syncthreads();

    // scores: lane -> (q = lane%3, t = lane/3); all 4 heads per lane
    if (lane < 60) {
      const int t = lane / 3, q = lane - t * 3;
      float acc[4] = {0.f, 0.f, 0.f, 0.f};
#pragma unroll
      for (int dc = 0; dc < 32; ++dc) {
        const float2 kf = *reinterpret_cast<const float2*>(&k_s[t][dc * 2]);
        const float2 qf = *reinterpret_cast<const float2*>(&q_s[q][dc * 2]);
        acc[dc >> 3] += kf.x * qf.x + kf.y * qf.y;
      }
#pragma unroll
      for (int h = 0; h < 4; ++h) w_att[h * 3 + q][t] = acc[h] * 0.25f;
    }
    __syncthreads();

    // softmax over t per (h,q) row
    if (lane < 12) {
      float m = -1e30f;
#pragma unroll
      for (int t = 0; t < 20; ++t) m = fmaxf(m, w_att[lane][t]);
      float e[20], s = 0.f;
#pragma unroll
      for (int t = 0; t < 20; ++t) { e[t] = __expf(w_att[lane][t] - m); s += e[t]; }
      const float inv = 1.f / s;
#pragma unroll
      for (int t = 0; t < 20; ++t) w_att[lane][t] = e[t] * inv;
    }
    __syncthreads();

    // AV: lane = channel, v in registers
    {
      const int h3 = (lane >> 4) * 3;
      float oq[3] = {0.f, 0.f, 0.f};
#pragma unroll
      for (int t = 0; t < 20; ++t) {
        const float v = vacc[t];
        oq[0] = fmaf(w_att[h3 + 0][t], v, oq[0]);
        oq[1] = fmaf(w_att[h3 + 1][t], v, oq[1]);
        oq[2] = fmaf(w_att[h3 + 2][t], v, oq[2]);
      }
#pragma unroll
      for (int q = 0; q < 3; ++q) o_s[q][lane] = oq[q];
    }
    __syncthreads();

    // O-proj + residual + LayerNorm
    {
      const float* wo = l ? p.wo2 : p.wo1;
      const float* bo = l ? p.bo2 : p.bo1;
      const float* g = l ? p.n2_g : p.n1_g;
      const float* bb = l ? p.n2_b : p.n1_b;
      float acc[3];
#pragma unroll
      for (int q = 0; q < 3; ++q)
        acc[q] = bo[lane] + (l ? x_s[q][lane] : p.qemb[q * 64 + lane]);
#pragma unroll
      for (int jc = 0; jc < 16; ++jc) {
        float w[4];
#pragma unroll
        for (int r = 0; r < 4; ++r) w[r] = wo[(jc * 4 + r) * 64 + lane];
#pragma unroll
        for (int q = 0; q < 3; ++q) {
          const float4 ov = *reinterpret_cast<const float4*>(&o_s[q][jc * 4]);
          acc[q] = fmaf(ov.x, w[0], fmaf(ov.y, w[1], fmaf(ov.z, w[2], fmaf(ov.w, w[3], acc[q]))));
        }
      }
      const float gg = g[lane], bbv = bb[lane];
#pragma unroll
      for (int q = 0; q < 3; ++q) {
        const float v = acc[q];
        float s = v;
#pragma unroll
        for (int m = 32; m >= 1; m >>= 1) s += __shfl_xor(s, m);
        const float mu = s * (1.f / 64.f);
        const float d = v - mu;
        float s2 = d * d;
#pragma unroll
        for (int m = 32; m >= 1; m >>= 1) s2 += __shfl_xor(s2, m);
        const float inv = rsqrtf(s2 * (1.f / 64.f) + 1e-5f);
        const float xn = d * inv * gg + bbv;
        xq[q] = xn;
        x_s[q][lane] = xn;
      }
    }
    __syncthreads();
  }

  // FFN hidden: f1 = relu(x2 @ w1 + b1)   [3][128], lane handles m=lane and m=lane+64
  {
    float acc0[3], acc1[3];
    const float b0 = p.ffn_b1[lane], b1v = p.ffn_b1[64 + lane];
#pragma unroll
    for (int q = 0; q < 3; ++q) { acc0[q] = b0; acc1[q] = b1v; }
#pragma unroll
    for (int jc = 0; jc < 16; ++jc) {
      float w0[4], w1[4];
#pragma unroll
      for (int r = 0; r < 4; ++r) {
        w0[r] = p.ffn_w1[(jc * 4 + r) * 128 + lane];
        w1[r] = p.ffn_w1[(jc * 4 + r) * 128 + 64 + lane];
      }
#pragma unroll
      for (int q = 0; q < 3; ++q) {
        const float4 xv = *reinterpret_cast<const float4*>(&x_s[q][jc * 4]);
        acc0[q] = fmaf(xv.x, w0[0], fmaf(xv.y, w0[1], fmaf(xv.z, w0[2], fmaf(xv.w, w0[3], acc0[q]))));
        acc1[q] = fmaf(xv.x, w1[0], fmaf(xv.y, w1[1], fmaf(xv.z, w1[2], fmaf(xv.w, w1[3], acc1[q]))));
      }
    }
#pragma unroll
    for (int q = 0; q < 3; ++q) {
      f1_s[q][lane] = fmaxf(acc0[q], 0.f);
      f1_s[q][64 + lane] = fmaxf(acc1[q], 0.f);
    }
  }
  __syncthreads();

  // FFN out + residual + LN3 -> x3 in x_s
  {
    float acc[3];
#pragma unroll
    for (int q = 0; q < 3; ++q) acc[q] = p.ffn_b2[lane] + xq[q];
#pragma unroll
    for (int mc = 0; mc < 32; ++mc) {
      float w[4];
#pragma unroll
      for (int r = 0; r < 4; ++r) w[r] = p.ffn_w2[(mc * 4 + r) * 64 + lane];
#pragma unroll
      for (int q = 0; q < 3; ++q) {
        const float4 fv = *reinterpret_cast<const float4*>(&f1_s[q][mc * 4]);
        acc[q] = fmaf(fv.x, w[0], fmaf(fv.y, w[1], fmaf(fv.z, w[2], fmaf(fv.w, w[3], acc[q]))));
      }
    }
    const float gg = p.n3_g[lane], bbv = p.n3_b[lane];
#pragma unroll
    for (int q = 0; q < 3; ++q) {
      const float v = acc[q];
      float s = v;
#pragma unroll
      for (int m = 32; m >= 1; m >>= 1) s += __shfl_xor(s, m);
      const float mu = s * (1.f / 64.f);
      const float d = v - mu;
      float s2 = d * d;
#pragma unroll
      for (int m = 32; m >= 1; m >>= 1) s2 += __shfl_xor(s2, m);
      const float inv = rsqrtf(s2 * (1.f / 64.f) + 1e-5f);
      x_s[q][lane] = d * inv * gg + bbv;
    }
  }
  __syncthreads();

  // output head part 1: y1 = relu(x3 @ op_w1 + op_b1)  [3][32] -> o_s
  if (lane < 32) {
    float acc[3];
#pragma unroll
    for (int q = 0; q < 3; ++q) acc[q] = p.op_b1[lane];
#pragma unroll
    for (int jc = 0; jc < 16; ++jc) {
      float w[4];
#pragma unroll
      for (int r = 0; r < 4; ++r) w[r] = p.op_w1[(jc * 4 + r) * 32 + lane];
#pragma unroll
      for (int q = 0; q < 3; ++q) {
        const float4 xv = *reinterpret_cast<const float4*>(&x_s[q][jc * 4]);
        acc[q] = fmaf(xv.x, w[0], fmaf(xv.y, w[1], fmaf(xv.z, w[2], fmaf(xv.w, w[3], acc[q]))));
      }
    }
#pragma unroll
    for (int q = 0; q < 3; ++q) o_s[q][lane] = fmaxf(acc[q], 0.f);
  }
  __syncthreads();

  // output head part 2: out = y1 @ op_w2 + op_b2  [3][2]
  if (lane < 6) {
    const int q = lane >> 1, e = lane & 1;
    float acc = p.op_b2[e];
#pragma unroll
    for (int m = 0; m < 32; ++m) acc = fmaf(o_s[q][m], p.op_w2[m * 2 + e], acc);
    p.out[item * 6 + q * 2 + e] = acc;
  }
}

extern "C" void kernel_launch(void* const* d_in, const int* in_sizes, int n_in,
                              void* d_out, int out_size, void* d_ws, size_t ws_size,
                              hipStream_t stream) {
  const float* in[40];
  for (int i = 0; i < n_in && i < 40; ++i) in[i] = (const float*)d_in[i];

  // attention param block ordering: dict order (w,w,w,w,b,b,b,b) vs signature (w,b,w,b,...)
  const float *a1_wq, *a1_wk, *a1_wv, *a1_wo, *a1_bq, *a1_bk, *a1_bv, *a1_bo;
  const float *a2_wq, *a2_wk, *a2_wv, *a2_wo, *a2_bq, *a2_bk, *a2_bv, *a2_bo;
  if (in_sizes[8] == 4096) {
    a1_wq = in[7];  a1_wk = in[8];  a1_wv = in[9];  a1_wo = in[10];
    a1_bq = in[11]; a1_bk = in[12]; a1_bv = in[13]; a1_bo = in[14];
    a2_wq = in[15]; a2_wk = in[16]; a2_wv = in[17]; a2_wo = in[18];
    a2_bq = in[19]; a2_bk = in[20]; a2_bv = in[21]; a2_bo = in[22];
  } else {
    a1_wq = in[7];  a1_bq = in[8];  a1_wk = in[9];  a1_bk = in[10];
    a1_wv = in[11]; a1_bv = in[12]; a1_wo = in[13]; a1_bo = in[14];
    a2_wq = in[15]; a2_bq = in[16]; a2_wk = in[17]; a2_bk = in[18];
    a2_wv = in[19]; a2_bv = in[20]; a2_wo = in[21]; a2_bo = in[22];
  }

  float* ws = (float*)d_ws;
  prep_kernel<<<33, 256, 0, stream>>>(in[5], in[6], a1_wk, a1_bk, a1_wv, a1_bv,
                                      a2_wk, a2_bk, a2_wv, a2_bv, in[2], a1_wq, a1_bq, ws);

  Params p;
  p.tl = in[0]; p.tr = in[1]; p.qemb = in[2];
  p.ip_w1 = in[3]; p.ip_b1 = in[4];
  p.wq2 = a2_wq; p.bq2 = a2_bq;
  p.wo1 = a1_wo; p.bo1 = a1_bo;
  p.wo2 = a2_wo; p.bo2 = a2_bo;
  p.ffn_w1 = in[23]; p.ffn_b1 = in[24]; p.ffn_w2 = in[25]; p.ffn_b2 = in[26];
  p.n1_g = in[27]; p.n1_b = in[28]; p.n2_g = in[29]; p.n2_b = in[30];
  p.n3_g = in[31]; p.n3_b = in[32];
  p.op_w1 = in[33]; p.op_b1 = in[34]; p.op_w2 = in[35]; p.op_b2 = in[36];
  p.ws = ws; p.out = (float*)d_out;

  planner_kernel<<<32768, 64, 0, stream>>>(p);
}

// Round 3
// 376.852 us; speedup vs baseline: 1.2650x; 1.2650x over previous
//
#include <hip/hip_runtime.h>
#include <math.h>

#define SCALE 0.36067376022224085f  // 0.25 * log2(e): folded attn scale for exp2-domain softmax

// ws float offsets
#define WVF1F 0      // [32][64] folded ip_w2@wv (layer1)
#define WVF2F 2048   // [32][64] layer2
#define WKT2F 4096   // [64][32] transposed folded ip_w2@wk2, * SCALE
#define G1F   6144   // [12][32] g1[h*3+q][j] = SCALE * Wkf1[:,h16+d].q1  (layer-1 score weights)
#define BVF1F 6528   // [64] folded v bias layer1
#define BVF2F 6592   // [64] layer2

#define WSYNC() do { asm volatile("s_waitcnt lgkmcnt(0)" ::: "memory"); __builtin_amdgcn_wave_barrier(); } while (0)

struct Params {
  const float* tl; const float* tr; const float* qemb;
  const float* ip_w1; const float* ip_b1;
  const float* wq2; const float* bq2;
  const float* wo1; const float* bo1;
  const float* wo2; const float* bo2;
  const float* ffn_w1; const float* ffn_b1;
  const float* ffn_w2; const float* ffn_b2;
  const float* n1_g; const float* n1_b;
  const float* n2_g; const float* n2_b;
  const float* n3_g; const float* n3_b;
  const float* op_w1; const float* op_b1;
  const float* op_w2; const float* op_b2;
  const float* ws;
  float* out;
};

// Fold ip_w2 @ wv (both layers), transposed+scaled ip_w2 @ wk2, and folded v-biases.
__global__ void prep1_kernel(const float* ip_w2, const float* ip_b2,
                             const float* wk2, const float* wv1, const float* wv2,
                             const float* bv1, const float* bv2, float* ws) {
  const int bid = blockIdx.x, tid = threadIdx.x;
  if (bid < 24) {
    const int idx = bid * 256 + tid;      // 0..6143
    const int mat = idx >> 11;
    const int rem = idx & 2047;
    const int j = rem >> 6, c = rem & 63;
    const float* W = (mat == 0) ? wv1 : (mat == 1) ? wv2 : wk2;
    float acc = 0.f;
    for (int m = 0; m < 64; ++m) acc = fmaf(ip_w2[j * 64 + m], W[m * 64 + c], acc);
    if (mat == 0)      ws[WVF1F + j * 64 + c] = acc;
    else if (mat == 1) ws[WVF2F + j * 64 + c] = acc;
    else               ws[WKT2F + c * 32 + j] = acc * SCALE;   // transposed
  } else if (tid < 128) {
    const int l = tid >> 6, d = tid & 63;
    const float* bv = l ? bv2 : bv1;
    const float* wv = l ? wv2 : wv1;
    float acc = bv[d];
    for (int m = 0; m < 64; ++m) acc = fmaf(ip_b2[m], wv[m * 64 + d], acc);
    ws[(l ? BVF2F : BVF1F) + d] = acc;
  }
}

// g1[h*3+q][j] = SCALE * sum_d Wkf1[j][h*16+d] * q1[q][h*16+d]; q1 = qemb@wq1+bq1
__global__ void prep2_kernel(const float* ip_w2, const float* wk1,
                             const float* qemb, const float* wq1, const float* bq1,
                             float* ws) {
  __shared__ float wkf[32][64];
  __shared__ float q1[3][64];
  const int tid = threadIdx.x;   // block of 384
  for (int e = tid; e < 2048; e += 384) {
    const int j = e >> 6, c = e & 63;
    float acc = 0.f;
    for (int m = 0; m < 64; ++m) acc = fmaf(ip_w2[j * 64 + m], wk1[m * 64 + c], acc);
    wkf[j][c] = acc;
  }
  if (tid < 192) {
    const int q = tid >> 6, d = tid & 63;
    float acc = bq1[d];
    for (int e = 0; e < 64; ++e) acc = fmaf(qemb[q * 64 + e], wq1[e * 64 + d], acc);
    q1[q][d] = acc;
  }
  __syncthreads();
  {
    const int r = tid >> 5, j = tid & 31;   // r = h*3+q, 12 rows -> tid<384
    const int h = r / 3, q = r - h * 3;
    float acc = 0.f;
    for (int d = 0; d < 16; ++d) acc = fmaf(wkf[j][h * 16 + d], q1[q][h * 16 + d], acc);
    ws[G1F + r * 32 + j] = acc * SCALE;
  }
}

__global__ __launch_bounds__(256, 5) void planner_kernel(Params p) {
  const int w = threadIdx.x >> 6;
  const int lane = threadIdx.x & 63;
  const int item = blockIdx.x * 4 + w;

  // LDS: 31936 B -> 5 blocks/CU = 20 waves/CU
  __shared__ __align__(16) float g1_s[12][36];       // block-shared
  __shared__ __align__(16) float a_s[4][20][36];     // relu acts; later overlaid by f1[3][136]
  __shared__ __align__(16) float att_s[4][12][24];   // raw scores -> exp; [.][20]=1/sum
  __shared__ __align__(16) float ch_s[4][12][36];    // att@a (normalized); also holds g2
  __shared__ __align__(16) float qx_s[4][3][68];     // q2 / attn-out o / y1
  __shared__ __align__(16) float x_s[4][3][68];      // residual stream
  __shared__ float pts_s[4][40];

  const float* ws = p.ws;

  for (int e = threadIdx.x; e < 384; e += 256)
    g1_s[e >> 5][e & 31] = ws[G1F + e];

  if (lane < 40)
    pts_s[w][lane] = (lane < 20) ? p.tl[item * 20 + lane] : p.tr[item * 20 + lane - 20];
  WSYNC();

  // a = relu(pts @ ip_w1 + ip_b1)   [20][32]
  {
    const int j = lane & 31, th = lane >> 5;
    const float w0 = p.ip_w1[j], w1 = p.ip_w1[32 + j], b = p.ip_b1[j];
#pragma unroll
    for (int i = 0; i < 10; ++i) {
      const int t = th * 10 + i;
      a_s[w][t][j] = fmaxf(fmaf(pts_s[w][2 * t], w0, fmaf(pts_s[w][2 * t + 1], w1, b)), 0.f);
    }
  }
  __syncthreads();  // covers g1_s (cross-wave) and a_s

  const int t3 = lane / 3;
  const int q3 = lane - t3 * 3;
  const int j32 = lane & 31, half = lane >> 5, hq0 = half * 6;
  const int h16 = lane >> 4;

  float xq[3];

#pragma unroll
  for (int l = 0; l < 2; ++l) {
    if (l == 1) {
      // Q2 projection: lane = channel
      float acc[3];
#pragma unroll
      for (int q = 0; q < 3; ++q) acc[q] = p.bq2[lane];
#pragma unroll
      for (int jc = 0; jc < 16; ++jc) {
        float wv[4];
#pragma unroll
        for (int r = 0; r < 4; ++r) wv[r] = p.wq2[(jc * 4 + r) * 64 + lane];
#pragma unroll
        for (int q = 0; q < 3; ++q) {
          const float4 xv = *(const float4*)&x_s[w][q][jc * 4];
          acc[q] = fmaf(xv.x, wv[0], fmaf(xv.y, wv[1], fmaf(xv.z, wv[2], fmaf(xv.w, wv[3], acc[q]))));
        }
      }
#pragma unroll
      for (int q = 0; q < 3; ++q) qx_s[w][q][lane] = acc[q];
      WSYNC();
      // g2[h*3+q][j] = sum_D WkT2[D][j] * q2[q][D]   (SCALE folded in WkT2)
      {
        float g2[6] = {0, 0, 0, 0, 0, 0};
        const int D0 = half * 32;
#pragma unroll
        for (int dd = 0; dd < 32; ++dd) {
          const int D = D0 + dd;
          const float wk = ws[WKT2F + D * 32 + j32];
          const int hl = dd >> 4;
#pragma unroll
          for (int q = 0; q < 3; ++q)
            g2[hl * 3 + q] = fmaf(wk, qx_s[w][q][D], g2[hl * 3 + q]);
        }
#pragma unroll
        for (int k = 0; k < 6; ++k) ch_s[w][hq0 + k][j32] = g2[k];
      }
      WSYNC();
    }

    // scores: lane=(t,q), s[h] = sum_j a[t][j] * g[h*3+q][j]
    const float (*g)[36] = (l == 0) ? (const float (*)[36])g1_s : (const float (*)[36])ch_s[w];
    if (lane < 60) {
      float acc[4] = {0, 0, 0, 0};
#pragma unroll
      for (int jc = 0; jc < 8; ++jc) {
        const float4 av = *(const float4*)&a_s[w][t3][jc * 4];
#pragma unroll
        for (int h = 0; h < 4; ++h) {
          const float4 gv = *(const float4*)&g[h * 3 + q3][jc * 4];
          acc[h] = fmaf(av.x, gv.x, fmaf(av.y, gv.y, fmaf(av.z, gv.z, fmaf(av.w, gv.w, acc[h]))));
        }
      }
#pragma unroll
      for (int h = 0; h < 4; ++h) att_s[w][h * 3 + q3][t3] = acc[h];
    }
    WSYNC();

    // softmax rows (exp2 domain; scale folded upstream)
    if (lane < 12) {
      float m = -1e30f;
#pragma unroll
      for (int t = 0; t < 20; ++t) m = fmaxf(m, att_s[w][lane][t]);
      float s = 0.f;
#pragma unroll
      for (int t = 0; t < 20; ++t) {
        const float e = exp2f(att_s[w][lane][t] - m);
        att_s[w][lane][t] = e;
        s += e;
      }
      att_s[w][lane][20] = 1.f / s;
    }
    WSYNC();

    // ch[hq][j] = inv * sum_t att[hq][t] * a[t][j]; lane = (j, half of hq rows)
    {
      float c[6] = {0, 0, 0, 0, 0, 0};
#pragma unroll
      for (int tc = 0; tc < 5; ++tc) {
        float av[4];
#pragma unroll
        for (int r = 0; r < 4; ++r) av[r] = a_s[w][tc * 4 + r][j32];
#pragma unroll
        for (int k = 0; k < 6; ++k) {
          const float4 at = *(const float4*)&att_s[w][hq0 + k][tc * 4];
          c[k] = fmaf(at.x, av[0], fmaf(at.y, av[1], fmaf(at.z, av[2], fmaf(at.w, av[3], c[k]))));
        }
      }
#pragma unroll
      for (int k = 0; k < 6; ++k)
        ch_s[w][hq0 + k][j32] = c[k] * att_s[w][hq0 + k][20];
    }
    WSYNC();

    // o[q][d] = sum_j ch[h(d)*3+q][j] * Wvf[j][d] + bvf[d]
    {
      const float* Wv = ws + (l ? WVF2F : WVF1F);
      const float bv = ws[(l ? BVF2F : BVF1F) + lane];
      float o[3] = {bv, bv, bv};
#pragma unroll
      for (int jc = 0; jc < 8; ++jc) {
        float wv[4];
#pragma unroll
        for (int r = 0; r < 4; ++r) wv[r] = Wv[(jc * 4 + r) * 64 + lane];
#pragma unroll
        for (int q = 0; q < 3; ++q) {
          const float4 cv = *(const float4*)&ch_s[w][h16 * 3 + q][jc * 4];
          o[q] = fmaf(cv.x, wv[0], fmaf(cv.y, wv[1], fmaf(cv.z, wv[2], fmaf(cv.w, wv[3], o[q]))));
        }
      }
#pragma unroll
      for (int q = 0; q < 3; ++q) qx_s[w][q][lane] = o[q];
    }
    WSYNC();

    // O-proj + residual + LN
    {
      const float* wo = l ? p.wo2 : p.wo1;
      const float* bo = l ? p.bo2 : p.bo1;
      const float* gg = l ? p.n2_g : p.n1_g;
      const float* gb = l ? p.n2_b : p.n1_b;
      float acc[3];
#pragma unroll
      for (int q = 0; q < 3; ++q)
        acc[q] = bo[lane] + (l ? x_s[w][q][lane] : p.qemb[q * 64 + lane]);
#pragma unroll
      for (int jc = 0; jc < 16; ++jc) {
        float wv[4];
#pragma unroll
        for (int r = 0; r < 4; ++r) wv[r] = wo[(jc * 4 + r) * 64 + lane];
#pragma unroll
        for (int q = 0; q < 3; ++q) {
          const float4 ov = *(const float4*)&qx_s[w][q][jc * 4];
          acc[q] = fmaf(ov.x, wv[0], fmaf(ov.y, wv[1], fmaf(ov.z, wv[2], fmaf(ov.w, wv[3], acc[q]))));
        }
      }
      const float gv = gg[lane], bv = gb[lane];
#pragma unroll
      for (int q = 0; q < 3; ++q) {
        const float v = acc[q];
        float s = v;
#pragma unroll
        for (int m = 32; m >= 1; m >>= 1) s += __shfl_xor(s, m);
        const float mu = s * (1.f / 64.f);
        const float d = v - mu;
        float s2 = d * d;
#pragma unroll
        for (int m = 32; m >= 1; m >>= 1) s2 += __shfl_xor(s2, m);
        const float inv = rsqrtf(s2 * (1.f / 64.f) + 1e-5f);
        const float xn = fmaf(d * inv, gv, bv);
        xq[q] = xn;
        x_s[w][q][lane] = xn;
      }
    }
    WSYNC();
  }

  // FFN1: f1 = relu(x2 @ w1 + b1) -> overlay on a_s
  float* f1p = (float*)a_s[w];
  {
    float a0[3], a1[3];
    const float b0 = p.ffn_b1[lane], b1 = p.ffn_b1[64 + lane];
#pragma unroll
    for (int q = 0; q < 3; ++q) { a0[q] = b0; a1[q] = b1; }
#pragma unroll
    for (int jc = 0; jc < 16; ++jc) {
      float w0[4], w1[4];
#pragma unroll
      for (int r = 0; r < 4; ++r) {
        w0[r] = p.ffn_w1[(jc * 4 + r) * 128 + lane];
        w1[r] = p.ffn_w1[(jc * 4 + r) * 128 + 64 + lane];
      }
#pragma unroll
      for (int q = 0; q < 3; ++q) {
        const float4 xv = *(const float4*)&x_s[w][q][jc * 4];
        a0[q] = fmaf(xv.x, w0[0], fmaf(xv.y, w0[1], fmaf(xv.z, w0[2], fmaf(xv.w, w0[3], a0[q]))));
        a1[q] = fmaf(xv.x, w1[0], fmaf(xv.y, w1[1], fmaf(xv.z, w1[2], fmaf(xv.w, w1[3], a1[q]))));
      }
    }
#pragma unroll
    for (int q = 0; q < 3; ++q) {
      f1p[q * 136 + lane] = fmaxf(a0[q], 0.f);
      f1p[q * 136 + 64 + lane] = fmaxf(a1[q], 0.f);
    }
  }
  WSYNC();

  // FFN2 + residual + LN3
  {
    float acc[3];
#pragma unroll
    for (int q = 0; q < 3; ++q) acc[q] = p.ffn_b2[lane] + xq[q];
#pragma unroll
    for (int mc = 0; mc < 32; ++mc) {
      float wv[4];
#pragma unroll
      for (int r = 0; r < 4; ++r) wv[r] = p.ffn_w2[(mc * 4 + r) * 64 + lane];
#pragma unroll
      for (int q = 0; q < 3; ++q) {
        const float4 fv = *(const float4*)&f1p[q * 136 + mc * 4];
        acc[q] = fmaf(fv.x, wv[0], fmaf(fv.y, wv[1], fmaf(fv.z, wv[2], fmaf(fv.w, wv[3], acc[q]))));
      }
    }
    const float gv = p.n3_g[lane], bv = p.n3_b[lane];
#pragma unroll
    for (int q = 0; q < 3; ++q) {
      const float v = acc[q];
      float s = v;
#pragma unroll
      for (int m = 32; m >= 1; m >>= 1) s += __shfl_xor(s, m);
      const float mu = s * (1.f / 64.f);
      const float d = v - mu;
      float s2 = d * d;
#pragma unroll
      for (int m = 32; m >= 1; m >>= 1) s2 += __shfl_xor(s2, m);
      const float inv = rsqrtf(s2 * (1.f / 64.f) + 1e-5f);
      x_s[w][q][lane] = fmaf(d * inv, gv, bv);
    }
  }
  WSYNC();

  // head 1: y1 = relu(x3 @ op_w1 + op_b1) [3][32]
  if (lane < 32) {
    float acc[3];
#pragma unroll
    for (int q = 0; q < 3; ++q) acc[q] = p.op_b1[lane];
#pragma unroll
    for (int jc = 0; jc < 16; ++jc) {
      float wv[4];
#pragma unroll
      for (int r = 0; r < 4; ++r) wv[r] = p.op_w1[(jc * 4 + r) * 32 + lane];
#pragma unroll
      for (int q = 0; q < 3; ++q) {
        const float4 xv = *(const float4*)&x_s[w][q][jc * 4];
        acc[q] = fmaf(xv.x, wv[0], fmaf(xv.y, wv[1], fmaf(xv.z, wv[2], fmaf(xv.w, wv[3], acc[q]))));
      }
    }
#pragma unroll
    for (int q = 0; q < 3; ++q) qx_s[w][q][lane] = fmaxf(acc[q], 0.f);
  }
  WSYNC();

  if (lane < 6) {
    const int q = lane >> 1, e = lane & 1;
    float acc = p.op_b2[e];
#pragma unroll
    for (int m = 0; m < 32; ++m) acc = fmaf(qx_s[w][q][m], p.op_w2[m * 2 + e], acc);
    p.out[item * 6 + q * 2 + e] = acc;
  }
}

extern "C" void kernel_launch(void* const* d_in, const int* in_sizes, int n_in,
                              void* d_out, int out_size, void* d_ws, size_t ws_size,
                              hipStream_t stream) {
  const float* in[40];
  for (int i = 0; i < n_in && i < 40; ++i) in[i] = (const float*)d_in[i];

  const float *a1_wq, *a1_wk, *a1_wv, *a1_wo, *a1_bq, *a1_bk, *a1_bv, *a1_bo;
  const float *a2_wq, *a2_wk, *a2_wv, *a2_wo, *a2_bq, *a2_bk, *a2_bv, *a2_bo;
  if (in_sizes[8] == 4096) {
    a1_wq = in[7];  a1_wk = in[8];  a1_wv = in[9];  a1_wo = in[10];
    a1_bq = in[11]; a1_bk = in[12]; a1_bv = in[13]; a1_bo = in[14];
    a2_wq = in[15]; a2_wk = in[16]; a2_wv = in[17]; a2_wo = in[18];
    a2_bq = in[19]; a2_bk = in[20]; a2_bv = in[21]; a2_bo = in[22];
  } else {
    a1_wq = in[7];  a1_bq = in[8];  a1_wk = in[9];  a1_bk = in[10];
    a1_wv = in[11]; a1_bv = in[12]; a1_wo = in[13]; a1_bo = in[14];
    a2_wq = in[15]; a2_bq = in[16]; a2_wk = in[17]; a2_bk = in[18];
    a2_wv = in[19]; a2_bv = in[20]; a2_wo = in[21]; a2_bo = in[22];
  }
  (void)a1_bk; (void)a2_bk;  // K biases fold out of softmax exactly

  float* ws = (float*)d_ws;
  prep1_kernel<<<25, 256, 0, stream>>>(in[5], in[6], a2_wk, a1_wv, a2_wv, a1_bv, a2_bv, ws);
  prep2_kernel<<<1, 384, 0, stream>>>(in[5], a1_wk, in[2], a1_wq, a1_bq, ws);

  Params p;
  p.tl = in[0]; p.tr = in[1]; p.qemb = in[2];
  p.ip_w1 = in[3]; p.ip_b1 = in[4];
  p.wq2 = a2_wq; p.bq2 = a2_bq;
  p.wo1 = a1_wo; p.bo1 = a1_bo;
  p.wo2 = a2_wo; p.bo2 = a2_bo;
  p.ffn_w1 = in[23]; p.ffn_b1 = in[24]; p.ffn_w2 = in[25]; p.ffn_b2 = in[26];
  p.n1_g = in[27]; p.n1_b = in[28]; p.n2_g = in[29]; p.n2_b = in[30];
  p.n3_g = in[31]; p.n3_b = in[32];
  p.op_w1 = in[33]; p.op_b1 = in[34]; p.op_w2 = in[35]; p.op_b2 = in[36];
  p.ws = ws; p.out = (float*)d_out;

  planner_kernel<<<8192, 256, 0, stream>>>(p);
}

// Round 4
// 258.092 us; speedup vs baseline: 1.8471x; 1.4601x over previous
//
#include <hip/hip_runtime.h>
#include <math.h>

#define SCALE 0.36067376022224085f  // 0.25 * log2(e): folded attn scale for exp2-domain softmax

// ws float offsets
#define WVF1F 0      // [32][64] folded ip_w2@wv (layer1)
#define WVF2F 2048   // [32][64] layer2
#define WKT2F 4096   // [64][32] transposed folded ip_w2@wk2, * SCALE
#define G1F   6144   // [12][32] g1[h*3+q][j] = SCALE * Wkf1[:,h16+d].q1  (layer-1 score weights)
#define BVF1F 6528   // [64] folded v bias layer1
#define BVF2F 6592   // [64] layer2

#define WSYNC() do { asm volatile("s_waitcnt lgkmcnt(0)" ::: "memory"); __builtin_amdgcn_wave_barrier(); } while (0)

struct Params {
  const float* tl; const float* tr; const float* qemb;
  const float* ip_w1; const float* ip_b1;
  const float* wq2; const float* bq2;
  const float* wo1; const float* bo1;
  const float* wo2; const float* bo2;
  const float* ffn_w1; const float* ffn_b1;
  const float* ffn_w2; const float* ffn_b2;
  const float* n1_g; const float* n1_b;
  const float* n2_g; const float* n2_b;
  const float* n3_g; const float* n3_b;
  const float* op_w1; const float* op_b1;
  const float* op_w2; const float* op_b2;
  const float* ws;
  float* out;
};

// Fold ip_w2 @ wv (both layers), transposed+scaled ip_w2 @ wk2, and folded v-biases.
__global__ void prep1_kernel(const float* ip_w2, const float* ip_b2,
                             const float* wk2, const float* wv1, const float* wv2,
                             const float* bv1, const float* bv2, float* ws) {
  const int bid = blockIdx.x, tid = threadIdx.x;
  if (bid < 24) {
    const int idx = bid * 256 + tid;      // 0..6143
    const int mat = idx >> 11;
    const int rem = idx & 2047;
    const int j = rem >> 6, c = rem & 63;
    const float* W = (mat == 0) ? wv1 : (mat == 1) ? wv2 : wk2;
    float acc = 0.f;
    for (int m = 0; m < 64; ++m) acc = fmaf(ip_w2[j * 64 + m], W[m * 64 + c], acc);
    if (mat == 0)      ws[WVF1F + j * 64 + c] = acc;
    else if (mat == 1) ws[WVF2F + j * 64 + c] = acc;
    else               ws[WKT2F + c * 32 + j] = acc * SCALE;   // transposed
  } else if (tid < 128) {
    const int l = tid >> 6, d = tid & 63;
    const float* bv = l ? bv2 : bv1;
    const float* wv = l ? wv2 : wv1;
    float acc = bv[d];
    for (int m = 0; m < 64; ++m) acc = fmaf(ip_b2[m], wv[m * 64 + d], acc);
    ws[(l ? BVF2F : BVF1F) + d] = acc;
  }
}

// g1[h*3+q][j] = SCALE * sum_d Wkf1[j][h*16+d] * q1[q][h*16+d]; q1 = qemb@wq1+bq1
__global__ void prep2_kernel(const float* ip_w2, const float* wk1,
                             const float* qemb, const float* wq1, const float* bq1,
                             float* ws) {
  __shared__ float wkf[32][64];
  __shared__ float q1[3][64];
  const int tid = threadIdx.x;   // block of 384
  for (int e = tid; e < 2048; e += 384) {
    const int j = e >> 6, c = e & 63;
    float acc = 0.f;
    for (int m = 0; m < 64; ++m) acc = fmaf(ip_w2[j * 64 + m], wk1[m * 64 + c], acc);
    wkf[j][c] = acc;
  }
  if (tid < 192) {
    const int q = tid >> 6, d = tid & 63;
    float acc = bq1[d];
    for (int e = 0; e < 64; ++e) acc = fmaf(qemb[q * 64 + e], wq1[e * 64 + d], acc);
    q1[q][d] = acc;
  }
  __syncthreads();
  {
    const int r = tid >> 5, j = tid & 31;   // r = h*3+q, 12 rows -> tid<384
    const int h = r / 3, q = r - h * 3;
    float acc = 0.f;
    for (int d = 0; d < 16; ++d) acc = fmaf(wkf[j][h * 16 + d], q1[q][h * 16 + d], acc);
    ws[G1F + r * 32 + j] = acc * SCALE;
  }
}

// __launch_bounds__(256) ONLY: (256,5) forced a 48-VGPR budget -> massive scratch
// spills (359 MB WRITE_SIZE/dispatch, HBM-bound at 420 us). Natural allocation
// (~90 VGPR) still reaches 4-5 blocks/CU via LDS=31.9KB.
__global__ __launch_bounds__(256) void planner_kernel(Params p) {
  const int w = threadIdx.x >> 6;
  const int lane = threadIdx.x & 63;
  const int item = blockIdx.x * 4 + w;

  __shared__ __align__(16) float g1_s[12][36];       // block-shared
  __shared__ __align__(16) float a_s[4][20][36];     // relu acts; later overlaid by f1[3][136]
  __shared__ __align__(16) float att_s[4][12][24];   // raw scores -> exp; [.][20]=1/sum
  __shared__ __align__(16) float ch_s[4][12][36];    // att@a (normalized); also holds g2
  __shared__ __align__(16) float qx_s[4][3][68];     // q2 / attn-out o / y1
  __shared__ __align__(16) float x_s[4][3][68];      // residual stream
  __shared__ float pts_s[4][40];

  const float* ws = p.ws;

  for (int e = threadIdx.x; e < 384; e += 256)
    g1_s[e >> 5][e & 31] = ws[G1F + e];

  if (lane < 40)
    pts_s[w][lane] = (lane < 20) ? p.tl[item * 20 + lane] : p.tr[item * 20 + lane - 20];
  WSYNC();

  // a = relu(pts @ ip_w1 + ip_b1)   [20][32]
  {
    const int j = lane & 31, th = lane >> 5;
    const float w0 = p.ip_w1[j], w1 = p.ip_w1[32 + j], b = p.ip_b1[j];
#pragma unroll
    for (int i = 0; i < 10; ++i) {
      const int t = th * 10 + i;
      a_s[w][t][j] = fmaxf(fmaf(pts_s[w][2 * t], w0, fmaf(pts_s[w][2 * t + 1], w1, b)), 0.f);
    }
  }
  __syncthreads();  // covers g1_s (cross-wave) and a_s

  const int t3 = lane / 3;
  const int q3 = lane - t3 * 3;
  const int j32 = lane & 31, half = lane >> 5, hq0 = half * 6;
  const int h16 = lane >> 4;

  float xq[3];

#pragma unroll
  for (int l = 0; l < 2; ++l) {
    if (l == 1) {
      // Q2 projection: lane = channel
      float acc[3];
#pragma unroll
      for (int q = 0; q < 3; ++q) acc[q] = p.bq2[lane];
#pragma unroll
      for (int jc = 0; jc < 16; ++jc) {
        float wv[4];
#pragma unroll
        for (int r = 0; r < 4; ++r) wv[r] = p.wq2[(jc * 4 + r) * 64 + lane];
#pragma unroll
        for (int q = 0; q < 3; ++q) {
          const float4 xv = *(const float4*)&x_s[w][q][jc * 4];
          acc[q] = fmaf(xv.x, wv[0], fmaf(xv.y, wv[1], fmaf(xv.z, wv[2], fmaf(xv.w, wv[3], acc[q]))));
        }
      }
#pragma unroll
      for (int q = 0; q < 3; ++q) qx_s[w][q][lane] = acc[q];
      WSYNC();
      // g2[h*3+q][j] = sum_D WkT2[D][j] * q2[q][D]   (SCALE folded in WkT2)
      {
        float g2[6] = {0, 0, 0, 0, 0, 0};
        const int D0 = half * 32;
#pragma unroll
        for (int dd = 0; dd < 32; ++dd) {
          const int D = D0 + dd;
          const float wk = ws[WKT2F + D * 32 + j32];
          const int hl = dd >> 4;
#pragma unroll
          for (int q = 0; q < 3; ++q)
            g2[hl * 3 + q] = fmaf(wk, qx_s[w][q][D], g2[hl * 3 + q]);
        }
#pragma unroll
        for (int k = 0; k < 6; ++k) ch_s[w][hq0 + k][j32] = g2[k];
      }
      WSYNC();
    }

    // scores: lane=(t,q), s[h] = sum_j a[t][j] * g[h*3+q][j]
    const float (*g)[36] = (l == 0) ? (const float (*)[36])g1_s : (const float (*)[36])ch_s[w];
    if (lane < 60) {
      float acc[4] = {0, 0, 0, 0};
#pragma unroll
      for (int jc = 0; jc < 8; ++jc) {
        const float4 av = *(const float4*)&a_s[w][t3][jc * 4];
#pragma unroll
        for (int h = 0; h < 4; ++h) {
          const float4 gv = *(const float4*)&g[h * 3 + q3][jc * 4];
          acc[h] = fmaf(av.x, gv.x, fmaf(av.y, gv.y, fmaf(av.z, gv.z, fmaf(av.w, gv.w, acc[h]))));
        }
      }
#pragma unroll
      for (int h = 0; h < 4; ++h) att_s[w][h * 3 + q3][t3] = acc[h];
    }
    WSYNC();

    // softmax rows (exp2 domain; scale folded upstream)
    if (lane < 12) {
      float m = -1e30f;
#pragma unroll
      for (int t = 0; t < 20; ++t) m = fmaxf(m, att_s[w][lane][t]);
      float s = 0.f;
#pragma unroll
      for (int t = 0; t < 20; ++t) {
        const float e = exp2f(att_s[w][lane][t] - m);
        att_s[w][lane][t] = e;
        s += e;
      }
      att_s[w][lane][20] = 1.f / s;
    }
    WSYNC();

    // ch[hq][j] = inv * sum_t att[hq][t] * a[t][j]; lane = (j, half of hq rows)
    {
      float c[6] = {0, 0, 0, 0, 0, 0};
#pragma unroll
      for (int tc = 0; tc < 5; ++tc) {
        float av[4];
#pragma unroll
        for (int r = 0; r < 4; ++r) av[r] = a_s[w][tc * 4 + r][j32];
#pragma unroll
        for (int k = 0; k < 6; ++k) {
          const float4 at = *(const float4*)&att_s[w][hq0 + k][tc * 4];
          c[k] = fmaf(at.x, av[0], fmaf(at.y, av[1], fmaf(at.z, av[2], fmaf(at.w, av[3], c[k]))));
        }
      }
#pragma unroll
      for (int k = 0; k < 6; ++k)
        ch_s[w][hq0 + k][j32] = c[k] * att_s[w][hq0 + k][20];
    }
    WSYNC();

    // o[q][d] = sum_j ch[h(d)*3+q][j] * Wvf[j][d] + bvf[d]
    {
      const float* Wv = ws + (l ? WVF2F : WVF1F);
      const float bv = ws[(l ? BVF2F : BVF1F) + lane];
      float o[3] = {bv, bv, bv};
#pragma unroll
      for (int jc = 0; jc < 8; ++jc) {
        float wv[4];
#pragma unroll
        for (int r = 0; r < 4; ++r) wv[r] = Wv[(jc * 4 + r) * 64 + lane];
#pragma unroll
        for (int q = 0; q < 3; ++q) {
          const float4 cv = *(const float4*)&ch_s[w][h16 * 3 + q][jc * 4];
          o[q] = fmaf(cv.x, wv[0], fmaf(cv.y, wv[1], fmaf(cv.z, wv[2], fmaf(cv.w, wv[3], o[q]))));
        }
      }
#pragma unroll
      for (int q = 0; q < 3; ++q) qx_s[w][q][lane] = o[q];
    }
    WSYNC();

    // O-proj + residual + LN
    {
      const float* wo = l ? p.wo2 : p.wo1;
      const float* bo = l ? p.bo2 : p.bo1;
      const float* gg = l ? p.n2_g : p.n1_g;
      const float* gb = l ? p.n2_b : p.n1_b;
      float acc[3];
#pragma unroll
      for (int q = 0; q < 3; ++q)
        acc[q] = bo[lane] + (l ? x_s[w][q][lane] : p.qemb[q * 64 + lane]);
#pragma unroll
      for (int jc = 0; jc < 16; ++jc) {
        float wv[4];
#pragma unroll
        for (int r = 0; r < 4; ++r) wv[r] = wo[(jc * 4 + r) * 64 + lane];
#pragma unroll
        for (int q = 0; q < 3; ++q) {
          const float4 ov = *(const float4*)&qx_s[w][q][jc * 4];
          acc[q] = fmaf(ov.x, wv[0], fmaf(ov.y, wv[1], fmaf(ov.z, wv[2], fmaf(ov.w, wv[3], acc[q]))));
        }
      }
      const float gv = gg[lane], bv = gb[lane];
#pragma unroll
      for (int q = 0; q < 3; ++q) {
        const float v = acc[q];
        float s = v;
#pragma unroll
        for (int m = 32; m >= 1; m >>= 1) s += __shfl_xor(s, m);
        const float mu = s * (1.f / 64.f);
        const float d = v - mu;
        float s2 = d * d;
#pragma unroll
        for (int m = 32; m >= 1; m >>= 1) s2 += __shfl_xor(s2, m);
        const float inv = rsqrtf(s2 * (1.f / 64.f) + 1e-5f);
        const float xn = fmaf(d * inv, gv, bv);
        xq[q] = xn;
        x_s[w][q][lane] = xn;
      }
    }
    WSYNC();
  }

  // FFN1: f1 = relu(x2 @ w1 + b1) -> overlay on a_s
  float* f1p = (float*)a_s[w];
  {
    float a0[3], a1[3];
    const float b0 = p.ffn_b1[lane], b1 = p.ffn_b1[64 + lane];
#pragma unroll
    for (int q = 0; q < 3; ++q) { a0[q] = b0; a1[q] = b1; }
#pragma unroll
    for (int jc = 0; jc < 16; ++jc) {
      float w0[4], w1[4];
#pragma unroll
      for (int r = 0; r < 4; ++r) {
        w0[r] = p.ffn_w1[(jc * 4 + r) * 128 + lane];
        w1[r] = p.ffn_w1[(jc * 4 + r) * 128 + 64 + lane];
      }
#pragma unroll
      for (int q = 0; q < 3; ++q) {
        const float4 xv = *(const float4*)&x_s[w][q][jc * 4];
        a0[q] = fmaf(xv.x, w0[0], fmaf(xv.y, w0[1], fmaf(xv.z, w0[2], fmaf(xv.w, w0[3], a0[q]))));
        a1[q] = fmaf(xv.x, w1[0], fmaf(xv.y, w1[1], fmaf(xv.z, w1[2], fmaf(xv.w, w1[3], a1[q]))));
      }
    }
#pragma unroll
    for (int q = 0; q < 3; ++q) {
      f1p[q * 136 + lane] = fmaxf(a0[q], 0.f);
      f1p[q * 136 + 64 + lane] = fmaxf(a1[q], 0.f);
    }
  }
  WSYNC();

  // FFN2 + residual + LN3
  {
    float acc[3];
#pragma unroll
    for (int q = 0; q < 3; ++q) acc[q] = p.ffn_b2[lane] + xq[q];
#pragma unroll
    for (int mc = 0; mc < 32; ++mc) {
      float wv[4];
#pragma unroll
      for (int r = 0; r < 4; ++r) wv[r] = p.ffn_w2[(mc * 4 + r) * 64 + lane];
#pragma unroll
      for (int q = 0; q < 3; ++q) {
        const float4 fv = *(const float4*)&f1p[q * 136 + mc * 4];
        acc[q] = fmaf(fv.x, wv[0], fmaf(fv.y, wv[1], fmaf(fv.z, wv[2], fmaf(fv.w, wv[3], acc[q]))));
      }
    }
    const float gv = p.n3_g[lane], bv = p.n3_b[lane];
#pragma unroll
    for (int q = 0; q < 3; ++q) {
      const float v = acc[q];
      float s = v;
#pragma unroll
      for (int m = 32; m >= 1; m >>= 1) s += __shfl_xor(s, m);
      const float mu = s * (1.f / 64.f);
      const float d = v - mu;
      float s2 = d * d;
#pragma unroll
      for (int m = 32; m >= 1; m >>= 1) s2 += __shfl_xor(s2, m);
      const float inv = rsqrtf(s2 * (1.f / 64.f) + 1e-5f);
      x_s[w][q][lane] = fmaf(d * inv, gv, bv);
    }
  }
  WSYNC();

  // head 1: y1 = relu(x3 @ op_w1 + op_b1) [3][32]
  if (lane < 32) {
    float acc[3];
#pragma unroll
    for (int q = 0; q < 3; ++q) acc[q] = p.op_b1[lane];
#pragma unroll
    for (int jc = 0; jc < 16; ++jc) {
      float wv[4];
#pragma unroll
      for (int r = 0; r < 4; ++r) wv[r] = p.op_w1[(jc * 4 + r) * 32 + lane];
#pragma unroll
      for (int q = 0; q < 3; ++q) {
        const float4 xv = *(const float4*)&x_s[w][q][jc * 4];
        acc[q] = fmaf(xv.x, wv[0], fmaf(xv.y, wv[1], fmaf(xv.z, wv[2], fmaf(xv.w, wv[3], acc[q]))));
      }
    }
#pragma unroll
    for (int q = 0; q < 3; ++q) qx_s[w][q][lane] = fmaxf(acc[q], 0.f);
  }
  WSYNC();

  if (lane < 6) {
    const int q = lane >> 1, e = lane & 1;
    float acc = p.op_b2[e];
#pragma unroll
    for (int m = 0; m < 32; ++m) acc = fmaf(qx_s[w][q][m], p.op_w2[m * 2 + e], acc);
    p.out[item * 6 + q * 2 + e] = acc;
  }
}

extern "C" void kernel_launch(void* const* d_in, const int* in_sizes, int n_in,
                              void* d_out, int out_size, void* d_ws, size_t ws_size,
                              hipStream_t stream) {
  const float* in[40];
  for (int i = 0; i < n_in && i < 40; ++i) in[i] = (const float*)d_in[i];

  const float *a1_wq, *a1_wk, *a1_wv, *a1_wo, *a1_bq, *a1_bk, *a1_bv, *a1_bo;
  const float *a2_wq, *a2_wk, *a2_wv, *a2_wo, *a2_bq, *a2_bk, *a2_bv, *a2_bo;
  if (in_sizes[8] == 4096) {
    a1_wq = in[7];  a1_wk = in[8];  a1_wv = in[9];  a1_wo = in[10];
    a1_bq = in[11]; a1_bk = in[12]; a1_bv = in[13]; a1_bo = in[14];
    a2_wq = in[15]; a2_wk = in[16]; a2_wv = in[17]; a2_wo = in[18];
    a2_bq = in[19]; a2_bk = in[20]; a2_bv = in[21]; a2_bo = in[22];
  } else {
    a1_wq = in[7];  a1_bq = in[8];  a1_wk = in[9];  a1_bk = in[10];
    a1_wv = in[11]; a1_bv = in[12]; a1_wo = in[13]; a1_bo = in[14];
    a2_wq = in[15]; a2_bq = in[16]; a2_wk = in[17]; a2_bk = in[18];
    a2_wv = in[19]; a2_bv = in[20]; a2_wo = in[21]; a2_bo = in[22];
  }
  (void)a1_bk; (void)a2_bk;  // K biases fold out of softmax exactly

  float* ws = (float*)d_ws;
  prep1_kernel<<<25, 256, 0, stream>>>(in[5], in[6], a2_wk, a1_wv, a2_wv, a1_bv, a2_bv, ws);
  prep2_kernel<<<1, 384, 0, stream>>>(in[5], a1_wk, in[2], a1_wq, a1_bq, ws);

  Params p;
  p.tl = in[0]; p.tr = in[1]; p.qemb = in[2];
  p.ip_w1 = in[3]; p.ip_b1 = in[4];
  p.wq2 = a2_wq; p.bq2 = a2_bq;
  p.wo1 = a1_wo; p.bo1 = a1_bo;
  p.wo2 = a2_wo; p.bo2 = a2_bo;
  p.ffn_w1 = in[23]; p.ffn_b1 = in[24]; p.ffn_w2 = in[25]; p.ffn_b2 = in[26];
  p.n1_g = in[27]; p.n1_b = in[28]; p.n2_g = in[29]; p.n2_b = in[30];
  p.n3_g = in[31]; p.n3_b = in[32];
  p.op_w1 = in[33]; p.op_b1 = in[34]; p.op_w2 = in[35]; p.op_b2 = in[36];
  p.ws = ws; p.out = (float*)d_out;

  planner_kernel<<<8192, 256, 0, stream>>>(p);
}